// Round 7
// baseline (182.200 us; speedup 1.0000x reference)
//
#include <hip/hip_runtime.h>

// PillarVFE fused.
// k1: block = 256 voxels. Coalesced LDS-staged point loads (8 dbuf rounds of
//     4 pts x 256 vox), per-thread masked moments P2(10)/T(4)/S(3),
//     algebraic epilogue -> 65 f-moments, block reduce -> partials row.
//     Last block (atomic counter) reduces all rows -> per-channel a,b (fused k2).
//     Also writes per-voxel packed record (-mean,-center bf16, cnt), coalesced.
// k3: A=[xyzw,-mean,-ctr]*mask in MFMA K-slots, B=a*W'' bf16, C=0 -> D=a*x;
//     out = relu(b + max_rows D). One wave = one voxel/iter, prefetched.

typedef __attribute__((ext_vector_type(8))) short short8;     // 8 bf16
typedef __attribute__((ext_vector_type(16))) float floatx16;  // 32x32 MFMA C/D

namespace {
constexpr int V_    = 100000;
constexpr int P_    = 32;
constexpr int COUT  = 64;
constexpr int NF    = 10;
constexpr int NMOM  = 65;
constexpr int PSTRIDE = 72;
constexpr int K1_BLOCKS = 391;    // ceil(100000/256) voxels, 1/thread
constexpr int K3_BLOCKS = 3125;   // 12500 waves x 8 iters = 100000 exactly
constexpr int K3_WAVES  = 12500;
constexpr int K3_ITERS  = 8;
constexpr int RSTRIDE   = 17;     // LDS row stride in dwords (4 pts x 4 + 1 pad)

constexpr float VX_ = 0.16f, VY_ = 0.16f, VZ_ = 4.0f;
constexpr float XOFF_ = 0.08f, YOFF_ = -39.60f, ZOFF_ = -1.0f;
constexpr float EPS_ = 0.001f;
}

__device__ __forceinline__ unsigned f2bfu(float x) {  // RNE -> 16-bit value
  unsigned u = __builtin_bit_cast(unsigned, x);
  u += 0x7fffu + ((u >> 16) & 1u);
  return u >> 16;
}

// ---------------- Pass 1 (+fused finalize) ----------------
__global__ __launch_bounds__(256) void k1_stats(
    const float* __restrict__ vf, const int* __restrict__ npts,
    const int* __restrict__ coords, float* __restrict__ partials,
    int4* __restrict__ meanws, unsigned* __restrict__ counter,
    const float* __restrict__ Wm, const float* __restrict__ gamma,
    const float* __restrict__ beta, float* __restrict__ ab)
{
  __shared__ float fs[2][256 * RSTRIDE];
  __shared__ float red[4][NMOM];
  __shared__ float s1[8][NMOM];
  __shared__ double Sd[NMOM];
  __shared__ unsigned lastFlag;

  const int tid = threadIdx.x;
  const int vbase = blockIdx.x * 256;
  const int v = vbase + tid;
  const bool valid = v < V_;

  int cnt = 0;
  int4 cd = make_int4(0, 0, 0, 0);
  if (valid) {
    cnt = npts[v];
    cd  = ((const int4*)coords)[v];
  }

  float p2[10];
  #pragma unroll
  for (int i = 0; i < 10; ++i) p2[i] = 0.f;
  float tx = 0.f, ty = 0.f, tz = 0.f, tw = 0.f;
  float sx = 0.f, sy = 0.f, sz = 0.f;

  // stage round 0 into buf 0
  float4 stg[4];
  #pragma unroll
  for (int i = 0; i < 4; ++i) {
    const int s  = tid + 256 * i;
    const int vo = s >> 2, pp = s & 3;
    const int vg = vbase + vo;
    stg[i] = (vg < V_) ? ((const float4*)vf)[(size_t)vg * P_ + pp]
                       : make_float4(0.f, 0.f, 0.f, 0.f);
  }
  #pragma unroll
  for (int i = 0; i < 4; ++i) {
    const int s = tid + 256 * i;
    const int ba = (s >> 2) * RSTRIDE + (s & 3) * 4;
    fs[0][ba] = stg[i].x; fs[0][ba+1] = stg[i].y;
    fs[0][ba+2] = stg[i].z; fs[0][ba+3] = stg[i].w;
  }
  __syncthreads();

  #pragma unroll
  for (int r = 0; r < 8; ++r) {
    // issue next round's global loads (no wait)
    if (r + 1 < 8) {
      #pragma unroll
      for (int i = 0; i < 4; ++i) {
        const int s  = tid + 256 * i;
        const int vo = s >> 2, pp = (r + 1) * 4 + (s & 3);
        const int vg = vbase + vo;
        stg[i] = (vg < V_) ? ((const float4*)vf)[(size_t)vg * P_ + pp]
                           : make_float4(0.f, 0.f, 0.f, 0.f);
      }
    }
    // compute own voxel's 4 points from LDS
    const float* buf = fs[r & 1];
    #pragma unroll
    for (int pp = 0; pp < 4; ++pp) {
      const int p = r * 4 + pp;
      const int ba = tid * RSTRIDE + pp * 4;
      const float qx = buf[ba], qy = buf[ba+1], qz = buf[ba+2], qw = buf[ba+3];
      const float msk = (p < cnt) ? 1.f : 0.f;
      sx += qx; sy += qy; sz += qz;
      const float ux = qx * msk, uy = qy * msk, uz = qz * msk, uw = qw * msk;
      tx += ux; ty += uy; tz += uz; tw += uw;
      p2[0] += ux*ux; p2[1] += ux*uy; p2[2] += ux*uz; p2[3] += ux*uw;
      p2[4] += uy*uy; p2[5] += uy*uz; p2[6] += uy*uw;
      p2[7] += uz*uz; p2[8] += uz*uw;
      p2[9] += uw*uw;
    }
    // write next round to the other buffer (waits for its loads here)
    if (r + 1 < 8) {
      float* nb = fs[(r + 1) & 1];
      #pragma unroll
      for (int i = 0; i < 4; ++i) {
        const int s = tid + 256 * i;
        const int ba = (s >> 2) * RSTRIDE + (s & 3) * 4;
        nb[ba] = stg[i].x; nb[ba+1] = stg[i].y;
        nb[ba+2] = stg[i].z; nb[ba+3] = stg[i].w;
      }
    }
    __syncthreads();
  }

  float mom[NMOM];
  if (valid) {
    const float cf = (float)cnt;
    const float rinv = 1.f / cf;
    const float gx = sx * rinv, gy = sy * rinv, gz = sz * rinv;
    const float hx = (float)cd.w * VX_ + XOFF_;
    const float hy = (float)cd.z * VY_ + YOFF_;
    const float hz = (float)cd.y * VZ_ + ZOFF_;

    // packed record for k3 (coalesced int4 store)
    unsigned nm01 = f2bfu(-gx) | (f2bfu(-gy) << 16);
    unsigned nm23 = f2bfu(-gz) | (f2bfu(-hx) << 16);
    unsigned nm45 = f2bfu(-hy) | (f2bfu(-hz) << 16);
    meanws[v] = make_int4((int)nm01, (int)nm23, (int)nm45, cnt);

    // f-moment reconstruction:
    // M1_i = T[SIG[i]] - cnt*K[i]
    // M2_ij = P2[SIG i,SIG j] - K_i*T[SIG j] - K_j*T[SIG i] + cnt*K_i*K_j
    const int SIG[10] = {0,1,2,3, 0,1,2, 0,1,2};
    const float K[10] = {0.f,0.f,0.f,0.f, gx,gy,gz, hx,hy,hz};
    const float Tm[4] = {tx,ty,tz,tw};
    const int I44[4][4] = {{0,1,2,3},{1,4,5,6},{2,5,7,8},{3,6,8,9}};

    #pragma unroll
    for (int i = 0; i < 10; ++i) mom[i] = Tm[SIG[i]] - cf * K[i];
    int idx = NF;
    #pragma unroll
    for (int i = 0; i < 10; ++i)
      #pragma unroll
      for (int j = i; j < 10; ++j) {
        mom[idx++] = p2[I44[SIG[i]][SIG[j]]]
                   - K[i] * Tm[SIG[j]] - K[j] * Tm[SIG[i]]
                   + cf * K[i] * K[j];
      }
  } else {
    #pragma unroll
    for (int i = 0; i < NMOM; ++i) mom[i] = 0.f;
  }

  // 64-lane butterfly + block reduce
  #pragma unroll
  for (int i = 0; i < NMOM; ++i) {
    float a = mom[i];
    #pragma unroll
    for (int m = 32; m >= 1; m >>= 1) a += __shfl_xor(a, m, 64);
    mom[i] = a;
  }
  if ((tid & 63) == 0) {
    int w = tid >> 6;
    #pragma unroll
    for (int i = 0; i < NMOM; ++i) red[w][i] = mom[i];
  }
  __syncthreads();
  if (tid < NMOM) {
    partials[blockIdx.x * PSTRIDE + tid] =
        (red[0][tid] + red[1][tid]) + (red[2][tid] + red[3][tid]);
  }
  __threadfence();   // make partials visible at device scope
  __syncthreads();
  if (tid == 0) {
    unsigned old = atomicAdd(counter, 1u);
    lastFlag = (old == (unsigned)(K1_BLOCKS - 1)) ? 1u : 0u;
  }
  __syncthreads();
  if (!lastFlag) return;
  __threadfence();   // acquire side

  // ---- fused finalize (last block only) ----
  for (int s = tid; s < 8 * NMOM; s += 256) {   // 520 slots: 8 chunks x 65 cols
    const int col = s % NMOM;
    const int ch  = s / NMOM;
    const int rbeg = ch * 49;
    const int rend = (rbeg + 49 < K1_BLOCKS) ? rbeg + 49 : K1_BLOCKS;
    float a[8];
    #pragma unroll
    for (int j = 0; j < 8; ++j) a[j] = 0.f;
    for (int r = rbeg; r < rend; r += 8) {
      #pragma unroll
      for (int j = 0; j < 8; ++j) {
        const int rr = r + j;
        if (rr < rend) a[j] += partials[rr * PSTRIDE + col];
      }
    }
    s1[ch][col] = (((a[0]+a[1]) + (a[2]+a[3])) + ((a[4]+a[5]) + (a[6]+a[7])));
  }
  __syncthreads();
  if (tid < NMOM) {
    double d = 0.0;
    #pragma unroll
    for (int c = 0; c < 8; ++c) d += (double)s1[c][tid];
    Sd[tid] = d;
  }
  __syncthreads();
  if (tid < COUT) {
    const double N = (double)V_ * (double)P_;
    double w[NF];
    #pragma unroll
    for (int c = 0; c < NF; ++c) w[c] = (double)Wm[tid * NF + c];
    double mean = 0.0;
    #pragma unroll
    for (int c = 0; c < NF; ++c) mean += w[c] * Sd[c];
    mean /= N;
    double ex2 = 0.0;
    int idx = NF;
    #pragma unroll
    for (int c = 0; c < NF; ++c)
      #pragma unroll
      for (int c2 = c; c2 < NF; ++c2) {
        double coef = (c == c2) ? 1.0 : 2.0;
        ex2 += coef * w[c] * w[c2] * Sd[idx++];
      }
    ex2 /= N;
    double var = ex2 - mean * mean;
    double rs = 1.0 / sqrt(var + (double)EPS_);
    double a = (double)gamma[tid] * rs;
    double b = (double)beta[tid] - mean * a;
    ab[tid] = (float)a;
    ab[COUT + tid] = (float)b;
  }
}

// ---------------- Pass 3 ----------------
__global__ __launch_bounds__(256) void k3_mfma(
    const float* __restrict__ vf, const float* __restrict__ Wm,
    const float* __restrict__ ab, const int4* __restrict__ meanws,
    float* __restrict__ out)
{
  const int tid  = threadIdx.x;
  const int lane = tid & 63;
  const int p    = lane & 31;
  const int half = lane >> 5;
  const int waveG = blockIdx.x * 4 + (tid >> 6);   // 0..12499

  // B fragments: B[k][n], n = lane&31, k = half*8+j.
  // k0..3: a*(W0+W4+W7, W1+W5+W8, W2+W6+W9, W3); k4..9: a*(W4..W9).
  const float a0 = ab[p],      b0 = ab[COUT + p];
  const float a1 = ab[32 + p], b1 = ab[COUT + 32 + p];
  short8 bf0, bf1;
  {
    const float* w0 = &Wm[p * NF];
    const float* w1 = &Wm[(32 + p) * NF];
    float t0[NF], t1[NF];
    t0[0] = a0 * (w0[0] + w0[4] + w0[7]);
    t0[1] = a0 * (w0[1] + w0[5] + w0[8]);
    t0[2] = a0 * (w0[2] + w0[6] + w0[9]);
    t0[3] = a0 * w0[3];
    t1[0] = a1 * (w1[0] + w1[4] + w1[7]);
    t1[1] = a1 * (w1[1] + w1[5] + w1[8]);
    t1[2] = a1 * (w1[2] + w1[6] + w1[9]);
    t1[3] = a1 * w1[3];
    #pragma unroll
    for (int k = 4; k < NF; ++k) { t0[k] = a0 * w0[k]; t1[k] = a1 * w1[k]; }

    uint4 bd0, bd1;
    unsigned p001 = f2bfu(t0[0]) | (f2bfu(t0[1]) << 16);
    unsigned p023 = f2bfu(t0[2]) | (f2bfu(t0[3]) << 16);
    unsigned p045 = f2bfu(t0[4]) | (f2bfu(t0[5]) << 16);
    unsigned p067 = f2bfu(t0[6]) | (f2bfu(t0[7]) << 16);
    unsigned p089 = f2bfu(t0[8]) | (f2bfu(t0[9]) << 16);
    unsigned p101 = f2bfu(t1[0]) | (f2bfu(t1[1]) << 16);
    unsigned p123 = f2bfu(t1[2]) | (f2bfu(t1[3]) << 16);
    unsigned p145 = f2bfu(t1[4]) | (f2bfu(t1[5]) << 16);
    unsigned p167 = f2bfu(t1[6]) | (f2bfu(t1[7]) << 16);
    unsigned p189 = f2bfu(t1[8]) | (f2bfu(t1[9]) << 16);
    bd0.x = half ? p089 : p001;  bd0.y = half ? 0u : p023;
    bd0.z = half ? 0u : p045;    bd0.w = half ? 0u : p067;
    bd1.x = half ? p189 : p101;  bd1.y = half ? 0u : p123;
    bd1.z = half ? 0u : p145;    bd1.w = half ? 0u : p167;
    bf0 = __builtin_bit_cast(short8, bd0);
    bf1 = __builtin_bit_cast(short8, bd1);
  }

  // prefetch iteration 0
  int vu = __builtin_amdgcn_readfirstlane(waveG);
  int4   rec_n = meanws[vu];
  float4 pt_n  = ((const float4*)vf)[vu * P_ + p];

  #pragma unroll
  for (int it = 0; it < K3_ITERS; ++it) {
    const int4   rec = rec_n;
    const float4 pt  = pt_n;
    const int vcur = vu;
    if (it + 1 < K3_ITERS) {
      vu = __builtin_amdgcn_readfirstlane(waveG + (it + 1) * K3_WAVES);
      rec_n = meanws[vu];
      pt_n  = ((const float4*)vf)[vu * P_ + p];
    }

    const int cnt = rec.w;
    const bool pm = p < cnt;
    unsigned dx = f2bfu(pm ? pt.x : 0.f) | (f2bfu(pm ? pt.y : 0.f) << 16);
    unsigned dy = f2bfu(pm ? pt.z : 0.f) | (f2bfu(pm ? pt.w : 0.f) << 16);
    unsigned m01 = pm ? (unsigned)rec.x : 0u;
    unsigned m23 = pm ? (unsigned)rec.y : 0u;
    unsigned m45 = pm ? (unsigned)rec.z : 0u;
    uint4 adw;
    adw.x = half ? m45 : dx;
    adw.y = half ? 0u  : dy;
    adw.z = half ? 0u  : m01;
    adw.w = half ? 0u  : m23;
    short8 af = __builtin_bit_cast(short8, adw);

    floatx16 c0 = {}, c1 = {};
    c0 = __builtin_amdgcn_mfma_f32_32x32x16_bf16(af, bf0, c0, 0, 0, 0);
    c1 = __builtin_amdgcn_mfma_f32_32x32x16_bf16(af, bf1, c1, 0, 0, 0);

    float m0 = c0[0], m1 = c1[0];
    #pragma unroll
    for (int i = 1; i < 16; ++i) {
      m0 = fmaxf(m0, c0[i]);
      m1 = fmaxf(m1, c1[i]);
    }
    m0 = fmaxf(m0, __shfl_xor(m0, 32, 64));
    m1 = fmaxf(m1, __shfl_xor(m1, 32, 64));
    float y = half ? fmaxf(b1 + m1, 0.f) : fmaxf(b0 + m0, 0.f);
    out[vcur * COUT + lane] = y;
  }
}

extern "C" void kernel_launch(void* const* d_in, const int* in_sizes, int n_in,
                              void* d_out, int out_size, void* d_ws, size_t ws_size,
                              hipStream_t stream)
{
  const float* vf     = (const float*)d_in[0];
  const int*   npts   = (const int*)d_in[1];
  const int*   coords = (const int*)d_in[2];
  const float* Wm     = (const float*)d_in[3];
  const float* gamma  = (const float*)d_in[4];
  const float* beta   = (const float*)d_in[5];
  float* out = (float*)d_out;

  float* ws = (float*)d_ws;
  float*    partials = ws;                                  // 391*72 = 28152 floats
  float*    ab       = ws + K1_BLOCKS * PSTRIDE;            // 128 floats
  unsigned* counter  = (unsigned*)(ws + K1_BLOCKS * PSTRIDE + 128);      // idx 28280
  int4*     meanws   = (int4*)(ws + K1_BLOCKS * PSTRIDE + 132);          // idx 28284 (16B-aligned)

  hipMemsetAsync(counter, 0, sizeof(unsigned), stream);
  k1_stats<<<K1_BLOCKS, 256, 0, stream>>>(vf, npts, coords, partials, meanws,
                                          counter, Wm, gamma, beta, ab);
  k3_mfma<<<K3_BLOCKS, 256, 0, stream>>>(vf, Wm, ab, meanws, out);
}